// Round 13
// baseline (563.764 us; speedup 1.0000x reference)
//
#include <hip/hip_runtime.h>
#include <hip/hip_bf16.h>

typedef __attribute__((ext_vector_type(8))) short short8;
typedef __attribute__((ext_vector_type(4))) float f32x4;

#define D 256
#define MT 64
#define NW 8
#define GRID_MAIN 256
#define GV 16

#define BAR_LGKM asm volatile("s_waitcnt lgkmcnt(0)\ns_barrier" ::: "memory")

__device__ __forceinline__ unsigned pack2(float a, float b) {
    __hip_bfloat162 hh = __float22bfloat162_rn(make_float2(a, b));
    return *(unsigned*)&hh;
}
__device__ __forceinline__ float fast_sigmoid(float x) {
    return __builtin_amdgcn_rcpf(1.f + __expf(-x));
}
__device__ __forceinline__ void dma16(const void* g, void* lds) {
    __builtin_amdgcn_global_load_lds((const __attribute__((address_space(1))) unsigned int*)g,
                                     (__attribute__((address_space(3))) unsigned int*)lds, 16, 0, 0);
}
__device__ __forceinline__ void dma4(const void* g, void* lds) {
    __builtin_amdgcn_global_load_lds((const __attribute__((address_space(1))) unsigned int*)g,
                                     (__attribute__((address_space(3))) unsigned int*)lds, 4, 0, 0);
}

// K0: fused prep. blocks [0,128): feat_v ; [128,384): W_u->bf16 ; [384,...): zero rst
__global__ __launch_bounds__(256) void k_prep(
    const float* __restrict__ feat, const int* __restrict__ last_nodes,
    const float* __restrict__ Wv, const float* __restrict__ bv,
    const float* __restrict__ Wu, unsigned short* __restrict__ Wub,
    float* __restrict__ featv, float* __restrict__ rst, int Bseg, int nOut) {
    const int b = blockIdx.x;
    const int t = threadIdx.x;
    if (b < 128) {
        __shared__ float fln[GV][D];
        const int b0 = b * GV;
        for (int g = 0; g < GV; ++g) {
            int bb = b0 + g;
            int ln = (bb < Bseg) ? last_nodes[bb] : 0;
            fln[g][t] = feat[(long)ln * D + t];
        }
        __syncthreads();
        float acc[GV];
        float bvj = bv[t];
        #pragma unroll
        for (int g = 0; g < GV; ++g) acc[g] = bvj;
        const float* wr = Wv + (long)t * D;
        for (int k = 0; k < D; k += 4) {
            float4 w4 = *(const float4*)(wr + k);
            #pragma unroll
            for (int g = 0; g < GV; ++g) {
                acc[g] += w4.x * fln[g][k]     + w4.y * fln[g][k + 1]
                        + w4.z * fln[g][k + 2] + w4.w * fln[g][k + 3];
            }
        }
        for (int g = 0; g < GV; ++g)
            if (b0 + g < Bseg) featv[(long)(b0 + g) * D + t] = acc[g];
    } else if (b < 384) {
        int i = (b - 128) * 256 + t;
        if (i < D * D) Wub[i] = (unsigned short)(pack2(Wu[i], 0.f) & 0xffffu);
    } else {
        int base = (b - 384) * 1024 + t;
        #pragma unroll
        for (int it = 0; it < 4; ++it) {
            int i = base + it * 256;
            if (i < nOut) rst[i] = 0.f;
        }
    }
}

// K2: persistent fused kernel (round-10 skeleton).
//   Wave split: jg = w&1 owns j in [128jg,+128) (mt=8, a_reg=128 VGPR);
//               ng = w>>1 owns nodes [16ng,+16) (nt=1 -> 4x fewer B-frag reads).
//   DMA fp32 feat -> linear stage; convert -> XOR-swizzled bf16 tile.
//   One vmcnt(0)/iter (pre-convert); deferred atomics; fvr(t+1) after convert.
__global__ __launch_bounds__(512, 2) void k_main(
    const float* __restrict__ feat, const float* __restrict__ cnt,
    const int* __restrict__ seg, const unsigned short* __restrict__ Wub,
    const float* __restrict__ featv, const float* __restrict__ we,
    float* __restrict__ rst, int N) {

    __shared__ float stageF[MT][D];              // 64 KB, linear DMA dest
    __shared__ unsigned short Abuf[2][MT][D];    // 64 KB, swizzled bf16
    __shared__ int   seg_s[4][MT];
    __shared__ float cnt_s[4][MT];
    __shared__ float e_s[2][MT];                 // per-jg partials
    __shared__ float alpha_s[MT];
    __shared__ float we_s[D];                    // w_e staged in LDS (frees VGPRs)

    const int t  = threadIdx.x;
    const int w  = t >> 6;
    const int l  = t & 63;
    const int rl = l & 15;
    const int h  = l >> 4;
    const int jg = w & 1;       // j-group: [128jg, 128jg+128)
    const int ng = w >> 1;      // node-group: [16ng, 16ng+16)

    const int T   = (N + MT - 1) / MT;
    const int nb  = gridDim.x;
    const int per = T / nb, rem = T % nb;
    const int bid = blockIdx.x;
    const int c0  = bid * per + (bid < rem ? bid : rem);
    const int c1  = c0 + per + (bid < rem ? 1 : 0);
    if (c0 >= c1) return;

#define STAGE(ti)                                                             \
    {                                                                         \
        const long nb0 = (long)(ti) * MT;                                     \
        long nsx = nb0 + l; if (nsx > (long)N - 1) nsx = (long)N - 1;         \
        dma4(seg + nsx, &seg_s[(ti) & 3][0]);                                 \
        dma4(cnt + nsx, &cnt_s[(ti) & 3][0]);                                 \
        asm volatile("" ::: "memory");                                        \
        _Pragma("unroll")                                                     \
        for (int i = 0; i < 8; ++i) {                                         \
            int r = w + 8 * i;                                                \
            long nn = nb0 + r; if (nn > (long)N - 1) nn = (long)N - 1;        \
            dma16(feat + nn * D + 4 * l, &stageF[r][0]);                      \
        }                                                                     \
    }

#define CONVERT(buf)                                                          \
    {                                                                         \
        _Pragma("unroll")                                                     \
        for (int i = 0; i < 8; ++i) {                                         \
            int r = w + 8 * i;                                                \
            f32x4 fv = *(const f32x4*)&stageF[r][4 * l];                      \
            *(uint2*)&Abuf[buf][r][(((l >> 1) ^ (r & 7)) << 3) + ((l & 1) << 2)] = \
                make_uint2(pack2(fv[0], fv[1]), pack2(fv[2], fv[3]));         \
        }                                                                     \
    }

    // W_u rows [128jg, 128jg+128) resident in registers (128 VGPR)
    short8 a_reg[8][8];
    {
        const unsigned short* ab = Wub + (long)(128 * jg + rl) * D + h * 8;
        #pragma unroll
        for (int mt = 0; mt < 8; ++mt)
            #pragma unroll
            for (int s = 0; s < 8; ++s)
                a_reg[mt][s] = *(const short8*)(ab + (long)mt * 16 * D + s * 32);
    }

    // ---- prologue ----
    f32x4 fvr[8];
    STAGE(c0);
    if (t < D) we_s[t] = we[t];
    asm volatile("s_waitcnt vmcnt(0)" ::: "memory");
    CONVERT(c0 & 1);
    {
        int sg = seg_s[c0 & 3][16 * ng + rl];
        const float* fb = featv + (long)sg * D + 128 * jg + 4 * h;
        #pragma unroll
        for (int mt = 0; mt < 8; ++mt) fvr[mt] = *(const f32x4*)(fb + 16 * mt);
    }
    asm volatile("" ::: "memory");
    if (c0 + 1 < c1) STAGE(c0 + 1);
    BAR_LGKM;

    for (int tt = c0; tt < c1; ++tt) {
        const long n0 = (long)tt * MT;
        const bool more1 = (tt + 1 < c1);
        const bool more2 = (tt + 2 < c1);
        const int  cur   = tt & 1;
        const int* seg_t = seg_s[tt & 3];

        // s1: MFMA u[j][node]; A from regs (mt=8), B: wave's 16-node slice only
        f32x4 acc[8];
        #pragma unroll
        for (int mt = 0; mt < 8; ++mt) acc[mt] = (f32x4)0.f;

        const unsigned short* Ab = &Abuf[cur][0][0];
        __builtin_amdgcn_s_setprio(1);
        #pragma unroll
        for (int s = 0; s < 8; ++s) {
            const int R  = 16 * ng + rl;
            const int gr = (s * 4 + h) ^ (rl & 7);
            short8 bfr = *(const short8*)(Ab + R * D + gr * 8);
            #pragma unroll
            for (int mt = 0; mt < 8; ++mt)
                acc[mt] = __builtin_amdgcn_mfma_f32_16x16x32_bf16(a_reg[mt][s], bfr, acc[mt], 0, 0, 0);
        }
        __builtin_amdgcn_s_setprio(0);

        // s2: epilogue; lane's j = 128jg + 16mt + 4h + r, node = 16ng + rl
        {
            float ep = 0.f;
            #pragma unroll
            for (int mt = 0; mt < 8; ++mt) {
                f32x4 wv = *(const f32x4*)&we_s[128 * jg + 16 * mt + 4 * h];
                #pragma unroll
                for (int r = 0; r < 4; ++r)
                    ep += wv[r] * fast_sigmoid(acc[mt][r] + fvr[mt][r]);
            }
            ep += __shfl_xor(ep, 16);
            ep += __shfl_xor(ep, 32);
            if (h == 0) e_s[jg][16 * ng + rl] = ep;
        }
        BAR_LGKM;                                                       // b1

        // s3: alpha
        if (t < MT) {
            float e = e_s[0][t] + e_s[1][t];
            alpha_s[t] = (n0 + t < N) ? e * cnt_s[tt & 3][t] : 0.f;
        }
        BAR_LGKM;                                                       // b2

        // s4: P4 segment-sum from bf16 tile; final atomic pair deferred
        long rb_p = -1; float ca_p = 0.f, cb_p = 0.f;
        {
            const int p   = t & 127;
            const int gq  = t >> 7;
            const int i0  = gq * 16;
            const int nv  = (int)(((long)N - n0 < MT) ? ((long)N - n0) : MT);
            const int i1  = (i0 + 16 < nv) ? (i0 + 16) : nv;
            const unsigned* Ab32 = (const unsigned*)Ab;
            if (i0 < i1) {
                if ((i1 - i0) == 16 && seg_t[i0] == seg_t[i1 - 1]) {
                    float ca = 0.f, cb = 0.f, ca2 = 0.f, cb2 = 0.f;
                    #pragma unroll
                    for (int i2 = 0; i2 < 16; i2 += 2) {
                        int i = i0 + i2;
                        unsigned v0 = Ab32[(i + 0) * 128 + (((p >> 2) ^ ((i + 0) & 7)) << 2) + (p & 3)];
                        unsigned v1 = Ab32[(i + 1) * 128 + (((p >> 2) ^ ((i + 1) & 7)) << 2) + (p & 3)];
                        float a0 = alpha_s[i + 0], a1 = alpha_s[i + 1];
                        ca  += __uint_as_float(v0 << 16) * a0;
                        cb  += __uint_as_float(v0 & 0xffff0000u) * a0;
                        ca2 += __uint_as_float(v1 << 16) * a1;
                        cb2 += __uint_as_float(v1 & 0xffff0000u) * a1;
                    }
                    rb_p = (long)seg_t[i0] * D + 2 * p;
                    ca_p = ca + ca2; cb_p = cb + cb2;
                } else {
                    float ca = 0.f, cb = 0.f;
                    int curseg = seg_t[i0];
                    for (int i = i0; i < i1; ++i) {
                        int sgi = seg_t[i];
                        if (sgi != curseg) {
                            long rb = (long)curseg * D + 2 * p;
                            atomicAdd(&rst[rb], ca); atomicAdd(&rst[rb + 1], cb);
                            ca = cb = 0.f; curseg = sgi;
                        }
                        unsigned v = Ab32[i * 128 + (((p >> 2) ^ (i & 7)) << 2) + (p & 3)];
                        float al = alpha_s[i];
                        ca += __uint_as_float(v << 16) * al;
                        cb += __uint_as_float(v & 0xffff0000u) * al;
                    }
                    rb_p = (long)curseg * D + 2 * p;
                    ca_p = ca; cb_p = cb;
                }
            }
        }
        asm volatile("" ::: "memory");

        // s5: retire dma(t+1) (streamed all iteration); convert into Abuf[cur^1]
        if (more1) {
            asm volatile("s_waitcnt vmcnt(0)" ::: "memory");
            CONVERT((tt + 1) & 1);
        }

        // s6: deferred atomics (after the vmcnt(0) -> never waited fresh)
        if (rb_p >= 0) {
            atomicAdd(&rst[rb_p], ca_p);
            atomicAdd(&rst[rb_p + 1], cb_p);
        }
        asm volatile("" ::: "memory");

        // s7: fvr(t+1) — seg_s[(t+1)&3] retired by the vmcnt(0) above
        if (more1) {
            int sg = seg_s[(tt + 1) & 3][16 * ng + rl];
            const float* fb = featv + (long)sg * D + 128 * jg + 4 * h;
            #pragma unroll
            for (int mt = 0; mt < 8; ++mt) fvr[mt] = *(const f32x4*)(fb + 16 * mt);
            asm volatile("" ::: "memory");
        }

        // s8: issue DMA for tile t+2 (streams across all of iter t+1)
        if (more2) {
            STAGE(tt + 2);
            asm volatile("" ::: "memory");
        }
        BAR_LGKM;                                                       // b3
    }
#undef STAGE
#undef CONVERT
}

extern "C" void kernel_launch(void* const* d_in, const int* in_sizes, int n_in,
                              void* d_out, int out_size, void* d_ws, size_t ws_size,
                              hipStream_t stream) {
    const float* feat = (const float*)d_in[0];
    const float* cnt  = (const float*)d_in[1];
    const int*   segp = (const int*)d_in[2];
    const int*   last = (const int*)d_in[3];
    const float* Wu   = (const float*)d_in[4];
    const float* Wv   = (const float*)d_in[5];
    const float* bv   = (const float*)d_in[6];
    const float* we   = (const float*)d_in[7];
    float* rst = (float*)d_out;

    const int N    = in_sizes[1];
    const int Bseg = in_sizes[3];

    unsigned short* Wub   = (unsigned short*)d_ws;
    float*          featv = (float*)((char*)d_ws + (size_t)D * D * sizeof(unsigned short));

    const int zero_blocks = (out_size + 1023) / 1024;
    k_prep<<<384 + zero_blocks, 256, 0, stream>>>(feat, last, Wv, bv, Wu, Wub, featv, rst, Bseg, out_size);
    k_main<<<GRID_MAIN, 512, 0, stream>>>(feat, cnt, segp, Wub, featv, we, rst, N);
}

// Round 14
// 214.517 us; speedup vs baseline: 2.6281x; 2.6281x over previous
//
#include <hip/hip_runtime.h>
#include <hip/hip_bf16.h>

typedef __attribute__((ext_vector_type(8))) short short8;
typedef __attribute__((ext_vector_type(4))) float f32x4;

#define D 256
#define MT 64
#define NW 8
#define GRID_MAIN 256
#define GV 16

#define BAR_LGKM asm volatile("s_waitcnt lgkmcnt(0)\ns_barrier" ::: "memory")

__device__ __forceinline__ unsigned pack2(float a, float b) {
    __hip_bfloat162 hh = __float22bfloat162_rn(make_float2(a, b));
    return *(unsigned*)&hh;
}
__device__ __forceinline__ float fast_sigmoid(float x) {
    return __builtin_amdgcn_rcpf(1.f + __expf(-x));
}
__device__ __forceinline__ void dma16(const void* g, void* lds) {
    __builtin_amdgcn_global_load_lds((const __attribute__((address_space(1))) unsigned int*)g,
                                     (__attribute__((address_space(3))) unsigned int*)lds, 16, 0, 0);
}
__device__ __forceinline__ void dma4(const void* g, void* lds) {
    __builtin_amdgcn_global_load_lds((const __attribute__((address_space(1))) unsigned int*)g,
                                     (__attribute__((address_space(3))) unsigned int*)lds, 4, 0, 0);
}

// K0: fused prep. blocks [0,128): feat_v ; [128,384): W_u->bf16 ; [384,...): zero rst
__global__ __launch_bounds__(256) void k_prep(
    const float* __restrict__ feat, const int* __restrict__ last_nodes,
    const float* __restrict__ Wv, const float* __restrict__ bv,
    const float* __restrict__ Wu, unsigned short* __restrict__ Wub,
    float* __restrict__ featv, float* __restrict__ rst, int Bseg, int nOut) {
    const int b = blockIdx.x;
    const int t = threadIdx.x;
    if (b < 128) {
        __shared__ float fln[GV][D];
        const int b0 = b * GV;
        for (int g = 0; g < GV; ++g) {
            int bb = b0 + g;
            int ln = (bb < Bseg) ? last_nodes[bb] : 0;
            fln[g][t] = feat[(long)ln * D + t];
        }
        __syncthreads();
        float acc[GV];
        float bvj = bv[t];
        #pragma unroll
        for (int g = 0; g < GV; ++g) acc[g] = bvj;
        const float* wr = Wv + (long)t * D;
        for (int k = 0; k < D; k += 4) {
            float4 w4 = *(const float4*)(wr + k);
            #pragma unroll
            for (int g = 0; g < GV; ++g) {
                acc[g] += w4.x * fln[g][k]     + w4.y * fln[g][k + 1]
                        + w4.z * fln[g][k + 2] + w4.w * fln[g][k + 3];
            }
        }
        for (int g = 0; g < GV; ++g)
            if (b0 + g < Bseg) featv[(long)(b0 + g) * D + t] = acc[g];
    } else if (b < 384) {
        int i = (b - 128) * 256 + t;
        if (i < D * D) Wub[i] = (unsigned short)(pack2(Wu[i], 0.f) & 0xffffu);
    } else {
        int base = (b - 384) * 1024 + t;
        #pragma unroll
        for (int it = 0; it < 4; ++it) {
            int i = base + it * 256;
            if (i < nOut) rst[i] = 0.f;
        }
    }
}

// K2: persistent fused kernel (round-10 skeleton).
//   Wave split: jg = w&3 owns j in [64jg,+64) (mt=4, a_reg=64 VGPR);
//               ng = w>>2 owns nodes [32ng,+32) (nt=2 -> half the B-frag reads).
//   launch_bounds(512,1): no 128-VGPR cap; target alloc ~200 (2 waves/SIMD).
__global__ __launch_bounds__(512, 1) void k_main(
    const float* __restrict__ feat, const float* __restrict__ cnt,
    const int* __restrict__ seg, const unsigned short* __restrict__ Wub,
    const float* __restrict__ featv, const float* __restrict__ we,
    float* __restrict__ rst, int N) {

    __shared__ float stageF[MT][D];              // 64 KB, linear DMA dest
    __shared__ unsigned short Abuf[2][MT][D];    // 64 KB, swizzled bf16
    __shared__ int   seg_s[4][MT];
    __shared__ float cnt_s[4][MT];
    __shared__ float e_s[4][MT];                 // per-jg partials
    __shared__ float alpha_s[MT];
    __shared__ float we_s[D];

    const int t  = threadIdx.x;
    const int w  = t >> 6;
    const int l  = t & 63;
    const int rl = l & 15;
    const int h  = l >> 4;
    const int jg = w & 3;       // j-group: [64jg, 64jg+64)
    const int ng = w >> 2;      // node-group: [32ng, 32ng+32)

    const int T   = (N + MT - 1) / MT;
    const int nb  = gridDim.x;
    const int per = T / nb, rem = T % nb;
    const int bid = blockIdx.x;
    const int c0  = bid * per + (bid < rem ? bid : rem);
    const int c1  = c0 + per + (bid < rem ? 1 : 0);
    if (c0 >= c1) return;

#define STAGE(ti)                                                             \
    {                                                                         \
        const long nb0 = (long)(ti) * MT;                                     \
        long nsx = nb0 + l; if (nsx > (long)N - 1) nsx = (long)N - 1;         \
        dma4(seg + nsx, &seg_s[(ti) & 3][0]);                                 \
        dma4(cnt + nsx, &cnt_s[(ti) & 3][0]);                                 \
        asm volatile("" ::: "memory");                                        \
        _Pragma("unroll")                                                     \
        for (int i = 0; i < 8; ++i) {                                         \
            int r = w + 8 * i;                                                \
            long nn = nb0 + r; if (nn > (long)N - 1) nn = (long)N - 1;        \
            dma16(feat + nn * D + 4 * l, &stageF[r][0]);                      \
        }                                                                     \
    }

#define CONVERT(buf)                                                          \
    {                                                                         \
        _Pragma("unroll")                                                     \
        for (int i = 0; i < 8; ++i) {                                         \
            int r = w + 8 * i;                                                \
            f32x4 fv = *(const f32x4*)&stageF[r][4 * l];                      \
            *(uint2*)&Abuf[buf][r][(((l >> 1) ^ (r & 7)) << 3) + ((l & 1) << 2)] = \
                make_uint2(pack2(fv[0], fv[1]), pack2(fv[2], fv[3]));         \
        }                                                                     \
    }

    // W_u rows [64jg, 64jg+64) resident in registers (64 VGPR)
    short8 a_reg[4][8];
    {
        const unsigned short* ab = Wub + (long)(64 * jg + rl) * D + h * 8;
        #pragma unroll
        for (int mt = 0; mt < 4; ++mt)
            #pragma unroll
            for (int s = 0; s < 8; ++s)
                a_reg[mt][s] = *(const short8*)(ab + (long)mt * 16 * D + s * 32);
    }

    // ---- prologue ----
    f32x4 fvr[2][4];          // [nt][mt]
    STAGE(c0);
    if (t < D) we_s[t] = we[t];
    asm volatile("s_waitcnt vmcnt(0)" ::: "memory");
    CONVERT(c0 & 1);
    {
        #pragma unroll
        for (int nt = 0; nt < 2; ++nt) {
            int sg = seg_s[c0 & 3][32 * ng + 16 * nt + rl];
            const float* fb = featv + (long)sg * D + 64 * jg + 4 * h;
            #pragma unroll
            for (int mt = 0; mt < 4; ++mt) fvr[nt][mt] = *(const f32x4*)(fb + 16 * mt);
        }
    }
    asm volatile("" ::: "memory");
    if (c0 + 1 < c1) STAGE(c0 + 1);
    BAR_LGKM;

    for (int tt = c0; tt < c1; ++tt) {
        const long n0 = (long)tt * MT;
        const bool more1 = (tt + 1 < c1);
        const bool more2 = (tt + 2 < c1);
        const int  cur   = tt & 1;
        const int* seg_t = seg_s[tt & 3];

        // s1: MFMA u[j][node]; A from regs (mt=4), B: this wave's 32-node slice
        f32x4 acc[4][2];
        #pragma unroll
        for (int mt = 0; mt < 4; ++mt)
            #pragma unroll
            for (int nt = 0; nt < 2; ++nt) acc[mt][nt] = (f32x4)0.f;

        const unsigned short* Ab = &Abuf[cur][0][0];
        __builtin_amdgcn_s_setprio(1);
        #pragma unroll
        for (int s = 0; s < 8; ++s) {
            short8 bfr[2];
            #pragma unroll
            for (int nt = 0; nt < 2; ++nt) {
                const int R  = 32 * ng + 16 * nt + rl;
                const int gr = (s * 4 + h) ^ (rl & 7);
                bfr[nt] = *(const short8*)(Ab + R * D + gr * 8);
            }
            #pragma unroll
            for (int mt = 0; mt < 4; ++mt)
                #pragma unroll
                for (int nt = 0; nt < 2; ++nt)
                    acc[mt][nt] = __builtin_amdgcn_mfma_f32_16x16x32_bf16(a_reg[mt][s], bfr[nt], acc[mt][nt], 0, 0, 0);
        }
        __builtin_amdgcn_s_setprio(0);

        // s2: epilogue; lane's j = 64jg + 16mt + 4h + r, node = 32ng + 16nt + rl
        #pragma unroll
        for (int nt = 0; nt < 2; ++nt) {
            float ep = 0.f;
            #pragma unroll
            for (int mt = 0; mt < 4; ++mt) {
                f32x4 wv = *(const f32x4*)&we_s[64 * jg + 16 * mt + 4 * h];
                #pragma unroll
                for (int r = 0; r < 4; ++r)
                    ep += wv[r] * fast_sigmoid(acc[mt][nt][r] + fvr[nt][mt][r]);
            }
            ep += __shfl_xor(ep, 16);
            ep += __shfl_xor(ep, 32);
            if (h == 0) e_s[jg][32 * ng + 16 * nt + rl] = ep;
        }
        BAR_LGKM;                                                       // b1

        // s3: alpha
        if (t < MT) {
            float e = e_s[0][t] + e_s[1][t] + e_s[2][t] + e_s[3][t];
            alpha_s[t] = (n0 + t < N) ? e * cnt_s[tt & 3][t] : 0.f;
        }
        BAR_LGKM;                                                       // b2

        // s4: P4 segment-sum from bf16 tile; final atomic pair deferred
        long rb_p = -1; float ca_p = 0.f, cb_p = 0.f;
        {
            const int p   = t & 127;
            const int gq  = t >> 7;
            const int i0  = gq * 16;
            const int nv  = (int)(((long)N - n0 < MT) ? ((long)N - n0) : MT);
            const int i1  = (i0 + 16 < nv) ? (i0 + 16) : nv;
            const unsigned* Ab32 = (const unsigned*)Ab;
            if (i0 < i1) {
                if ((i1 - i0) == 16 && seg_t[i0] == seg_t[i1 - 1]) {
                    float ca = 0.f, cb = 0.f, ca2 = 0.f, cb2 = 0.f;
                    #pragma unroll
                    for (int i2 = 0; i2 < 16; i2 += 2) {
                        int i = i0 + i2;
                        unsigned v0 = Ab32[(i + 0) * 128 + (((p >> 2) ^ ((i + 0) & 7)) << 2) + (p & 3)];
                        unsigned v1 = Ab32[(i + 1) * 128 + (((p >> 2) ^ ((i + 1) & 7)) << 2) + (p & 3)];
                        float a0 = alpha_s[i + 0], a1 = alpha_s[i + 1];
                        ca  += __uint_as_float(v0 << 16) * a0;
                        cb  += __uint_as_float(v0 & 0xffff0000u) * a0;
                        ca2 += __uint_as_float(v1 << 16) * a1;
                        cb2 += __uint_as_float(v1 & 0xffff0000u) * a1;
                    }
                    rb_p = (long)seg_t[i0] * D + 2 * p;
                    ca_p = ca + ca2; cb_p = cb + cb2;
                } else {
                    float ca = 0.f, cb = 0.f;
                    int curseg = seg_t[i0];
                    for (int i = i0; i < i1; ++i) {
                        int sgi = seg_t[i];
                        if (sgi != curseg) {
                            long rb = (long)curseg * D + 2 * p;
                            atomicAdd(&rst[rb], ca); atomicAdd(&rst[rb + 1], cb);
                            ca = cb = 0.f; curseg = sgi;
                        }
                        unsigned v = Ab32[i * 128 + (((p >> 2) ^ (i & 7)) << 2) + (p & 3)];
                        float al = alpha_s[i];
                        ca += __uint_as_float(v << 16) * al;
                        cb += __uint_as_float(v & 0xffff0000u) * al;
                    }
                    rb_p = (long)curseg * D + 2 * p;
                    ca_p = ca; cb_p = cb;
                }
            }
        }
        asm volatile("" ::: "memory");

        // s5: retire dma(t+1) (streamed all iteration); convert into Abuf[cur^1]
        if (more1) {
            asm volatile("s_waitcnt vmcnt(0)" ::: "memory");
            CONVERT((tt + 1) & 1);
        }

        // s6: deferred atomics (after the vmcnt(0) -> never waited fresh)
        if (rb_p >= 0) {
            atomicAdd(&rst[rb_p], ca_p);
            atomicAdd(&rst[rb_p + 1], cb_p);
        }
        asm volatile("" ::: "memory");

        // s7: fvr(t+1) — seg_s[(t+1)&3] retired by the vmcnt(0) above
        if (more1) {
            #pragma unroll
            for (int nt = 0; nt < 2; ++nt) {
                int sg = seg_s[(tt + 1) & 3][32 * ng + 16 * nt + rl];
                const float* fb = featv + (long)sg * D + 64 * jg + 4 * h;
                #pragma unroll
                for (int mt = 0; mt < 4; ++mt) fvr[nt][mt] = *(const f32x4*)(fb + 16 * mt);
            }
            asm volatile("" ::: "memory");
        }

        // s8: issue DMA for tile t+2 (streams across all of iter t+1)
        if (more2) {
            STAGE(tt + 2);
            asm volatile("" ::: "memory");
        }
        BAR_LGKM;                                                       // b3
    }
#undef STAGE
#undef CONVERT
}

extern "C" void kernel_launch(void* const* d_in, const int* in_sizes, int n_in,
                              void* d_out, int out_size, void* d_ws, size_t ws_size,
                              hipStream_t stream) {
    const float* feat = (const float*)d_in[0];
    const float* cnt  = (const float*)d_in[1];
    const int*   segp = (const int*)d_in[2];
    const int*   last = (const int*)d_in[3];
    const float* Wu   = (const float*)d_in[4];
    const float* Wv   = (const float*)d_in[5];
    const float* bv   = (const float*)d_in[6];
    const float* we   = (const float*)d_in[7];
    float* rst = (float*)d_out;

    const int N    = in_sizes[1];
    const int Bseg = in_sizes[3];

    unsigned short* Wub   = (unsigned short*)d_ws;
    float*          featv = (float*)((char*)d_ws + (size_t)D * D * sizeof(unsigned short));

    const int zero_blocks = (out_size + 1023) / 1024;
    k_prep<<<384 + zero_blocks, 256, 0, stream>>>(feat, last, Wv, bv, Wu, Wub, featv, rst, Bseg, out_size);
    k_main<<<GRID_MAIN, 512, 0, stream>>>(feat, cnt, segp, Wub, featv, we, rst, N);
}

// Round 15
// 190.436 us; speedup vs baseline: 2.9604x; 1.1265x over previous
//
#include <hip/hip_runtime.h>
#include <hip/hip_bf16.h>

typedef __attribute__((ext_vector_type(8))) short short8;
typedef __attribute__((ext_vector_type(4))) float f32x4;

#define D 256
#define MT 64
#define NW 8
#define GRID_MAIN 256
#define GV 16

#define BAR_LGKM asm volatile("s_waitcnt lgkmcnt(0)\ns_barrier" ::: "memory")

__device__ __forceinline__ unsigned pack2(float a, float b) {
    __hip_bfloat162 hh = __float22bfloat162_rn(make_float2(a, b));
    return *(unsigned*)&hh;
}
__device__ __forceinline__ float fast_sigmoid(float x) {
    return __builtin_amdgcn_rcpf(1.f + __expf(-x));
}
__device__ __forceinline__ void dma16(const void* g, void* lds) {
    __builtin_amdgcn_global_load_lds((const __attribute__((address_space(1))) unsigned int*)g,
                                     (__attribute__((address_space(3))) unsigned int*)lds, 16, 0, 0);
}
__device__ __forceinline__ void dma4(const void* g, void* lds) {
    __builtin_amdgcn_global_load_lds((const __attribute__((address_space(1))) unsigned int*)g,
                                     (__attribute__((address_space(3))) unsigned int*)lds, 4, 0, 0);
}

// K0: fused prep. blocks [0,128): feat_v ; [128,384): W_u->bf16 ; [384,...): zero rst
__global__ __launch_bounds__(256) void k_prep(
    const float* __restrict__ feat, const int* __restrict__ last_nodes,
    const float* __restrict__ Wv, const float* __restrict__ bv,
    const float* __restrict__ Wu, unsigned short* __restrict__ Wub,
    float* __restrict__ featv, float* __restrict__ rst, int Bseg, int nOut) {
    const int b = blockIdx.x;
    const int t = threadIdx.x;
    if (b < 128) {
        __shared__ float fln[GV][D];
        const int b0 = b * GV;
        for (int g = 0; g < GV; ++g) {
            int bb = b0 + g;
            int ln = (bb < Bseg) ? last_nodes[bb] : 0;
            fln[g][t] = feat[(long)ln * D + t];
        }
        __syncthreads();
        float acc[GV];
        float bvj = bv[t];
        #pragma unroll
        for (int g = 0; g < GV; ++g) acc[g] = bvj;
        const float* wr = Wv + (long)t * D;
        for (int k = 0; k < D; k += 4) {
            float4 w4 = *(const float4*)(wr + k);
            #pragma unroll
            for (int g = 0; g < GV; ++g) {
                acc[g] += w4.x * fln[g][k]     + w4.y * fln[g][k + 1]
                        + w4.z * fln[g][k + 2] + w4.w * fln[g][k + 3];
            }
        }
        for (int g = 0; g < GV; ++g)
            if (b0 + g < Bseg) featv[(long)(b0 + g) * D + t] = acc[g];
    } else if (b < 384) {
        int i = (b - 128) * 256 + t;
        if (i < D * D) Wub[i] = (unsigned short)(pack2(Wu[i], 0.f) & 0xffffu);
    } else {
        int base = (b - 384) * 1024 + t;
        #pragma unroll
        for (int it = 0; it < 4; ++it) {
            int i = base + it * 256;
            if (i < nOut) rst[i] = 0.f;
        }
    }
}

// K2: persistent fused kernel (round-10 skeleton, wait-minimized).
//   DMA(t+1) streams fp32 feat -> linear stage across a FULL iteration;
//   convert (post-P4) builds the bf16 XOR-swizzled tile for iter t+1.
//   Manual waits: ONLY the pre-convert vmcnt(0) (retires one-iteration-old
//   DMA/atomics). Register-destined loads rely on compiler counted waits.
//   Iter tail order: convert -> fvr(t+1) -> deferred atomics -> STAGE(t+2).
__global__ __launch_bounds__(512, 2) void k_main(
    const float* __restrict__ feat, const float* __restrict__ cnt,
    const int* __restrict__ seg, const unsigned short* __restrict__ Wub,
    const float* __restrict__ featv, const float* __restrict__ we,
    float* __restrict__ rst, int N) {

    __shared__ float stageF[MT][D];              // 64 KB, linear DMA dest
    __shared__ unsigned short Abuf[2][MT][D];    // 64 KB, swizzled bf16
    __shared__ int   seg_s[4][MT];               // 4 slots: overwrite-race-free
    __shared__ float cnt_s[4][MT];
    __shared__ float e_s[NW][MT];
    __shared__ float alpha_s[MT];

    const int t  = threadIdx.x;
    const int w  = t >> 6;
    const int l  = t & 63;
    const int rl = l & 15;
    const int h  = l >> 4;

    const int T   = (N + MT - 1) / MT;
    const int nb  = gridDim.x;
    const int per = T / nb, rem = T % nb;
    const int bid = blockIdx.x;
    const int c0  = bid * per + (bid < rem ? bid : rem);
    const int c1  = c0 + per + (bid < rem ? 1 : 0);
    if (c0 >= c1) return;

#define STAGE(ti)                                                             \
    {                                                                         \
        const long nb0 = (long)(ti) * MT;                                     \
        long nsx = nb0 + l; if (nsx > (long)N - 1) nsx = (long)N - 1;         \
        dma4(seg + nsx, &seg_s[(ti) & 3][0]);                                 \
        dma4(cnt + nsx, &cnt_s[(ti) & 3][0]);                                 \
        asm volatile("" ::: "memory");                                        \
        _Pragma("unroll")                                                     \
        for (int i = 0; i < 8; ++i) {                                         \
            int r = w + 8 * i;                                                \
            long nn = nb0 + r; if (nn > (long)N - 1) nn = (long)N - 1;        \
            dma16(feat + nn * D + 4 * l, &stageF[r][0]);                      \
        }                                                                     \
    }

#define CONVERT(buf)                                                          \
    {                                                                         \
        _Pragma("unroll")                                                     \
        for (int i = 0; i < 8; ++i) {                                         \
            int r = w + 8 * i;                                                \
            f32x4 fv = *(const f32x4*)&stageF[r][4 * l];                      \
            *(uint2*)&Abuf[buf][r][(((l >> 1) ^ (r & 7)) << 3) + ((l & 1) << 2)] = \
                make_uint2(pack2(fv[0], fv[1]), pack2(fv[2], fv[3]));         \
        }                                                                     \
    }

    // W_u rows [32w, 32w+32) resident in registers (64 VGPR)
    short8 a_reg[2][8];
    {
        const unsigned short* ab = Wub + (long)(32 * w + rl) * D + h * 8;
        #pragma unroll
        for (int mt = 0; mt < 2; ++mt)
            #pragma unroll
            for (int s = 0; s < 8; ++s)
                a_reg[mt][s] = *(const short8*)(ab + (long)mt * 16 * D + s * 32);
    }
    f32x4 wev[2];
    wev[0] = *(const f32x4*)(we + 32 * w + h * 4);
    wev[1] = *(const f32x4*)(we + 32 * w + 16 + h * 4);

    // ---- prologue ----
    f32x4 fvr[2][4];
    STAGE(c0);
    asm volatile("s_waitcnt vmcnt(0)" ::: "memory");
    CONVERT(c0 & 1);
    {
        #pragma unroll
        for (int nt = 0; nt < 4; ++nt) {
            int sg = seg_s[c0 & 3][nt * 16 + rl];
            const float* fb = featv + (long)sg * D + 32 * w + h * 4;
            fvr[0][nt] = *(const f32x4*)(fb);
            fvr[1][nt] = *(const f32x4*)(fb + 16);
        }
    }
    asm volatile("" ::: "memory");
    if (c0 + 1 < c1) STAGE(c0 + 1);
    BAR_LGKM;

    for (int tt = c0; tt < c1; ++tt) {
        const long n0 = (long)tt * MT;
        const bool more1 = (tt + 1 < c1);
        const bool more2 = (tt + 2 < c1);
        const int  cur   = tt & 1;
        const int* seg_t = seg_s[tt & 3];

        // s1: MFMA u[j][node]; A from regs, B from bf16 swizzled LDS.
        //     No manual vmem wait: Abuf[cur] was converted + barriered.
        f32x4 acc[2][4];
        #pragma unroll
        for (int mt = 0; mt < 2; ++mt)
            #pragma unroll
            for (int nt = 0; nt < 4; ++nt) acc[mt][nt] = (f32x4)0.f;

        const unsigned short* Ab = &Abuf[cur][0][0];
        #pragma unroll
        for (int s = 0; s < 8; ++s) {
            short8 bfr[4];
            #pragma unroll
            for (int nt = 0; nt < 4; ++nt) {
                int R  = nt * 16 + rl;
                int gr = (s * 4 + h) ^ (rl & 7);
                bfr[nt] = *(const short8*)(Ab + R * D + gr * 8);
            }
            #pragma unroll
            for (int mt = 0; mt < 2; ++mt)
                #pragma unroll
                for (int nt = 0; nt < 4; ++nt)
                    acc[mt][nt] = __builtin_amdgcn_mfma_f32_16x16x32_bf16(a_reg[mt][s], bfr[nt], acc[mt][nt], 0, 0, 0);
        }

        // s2: epilogue; lane's j = 32w + 16mt + 4h + r, node = 16nt + rl
        //     (compiler inserts the counted wait for fvr's loads here)
        float ep[4] = {0.f, 0.f, 0.f, 0.f};
        #pragma unroll
        for (int mt = 0; mt < 2; ++mt)
            #pragma unroll
            for (int nt = 0; nt < 4; ++nt)
                #pragma unroll
                for (int r = 0; r < 4; ++r)
                    ep[nt] += wev[mt][r] * fast_sigmoid(acc[mt][nt][r] + fvr[mt][nt][r]);
        #pragma unroll
        for (int nt = 0; nt < 4; ++nt) {
            ep[nt] += __shfl_xor(ep[nt], 16);
            ep[nt] += __shfl_xor(ep[nt], 32);
        }
        if (h == 0) {
            #pragma unroll
            for (int nt = 0; nt < 4; ++nt) e_s[w][nt * 16 + rl] = ep[nt];
        }
        BAR_LGKM;                                                       // b1

        // s3: alpha (cnt_s[tt&3] retired by the pre-convert vmcnt(0) last iter)
        if (t < MT) {
            float e = 0.f;
            #pragma unroll
            for (int q = 0; q < NW; ++q) e += e_s[q][t];
            alpha_s[t] = (n0 + t < N) ? e * cnt_s[tt & 3][t] : 0.f;
        }
        BAR_LGKM;                                                       // b2

        // s4: P4 segment-sum from bf16 tile; final atomic pair deferred
        long rb_p = -1; float ca_p = 0.f, cb_p = 0.f;
        {
            const int p   = t & 127;
            const int gq  = t >> 7;
            const int i0  = gq * 16;
            const int nv  = (int)(((long)N - n0 < MT) ? ((long)N - n0) : MT);
            const int i1  = (i0 + 16 < nv) ? (i0 + 16) : nv;
            const unsigned* Ab32 = (const unsigned*)Ab;
            if (i0 < i1) {
                if ((i1 - i0) == 16 && seg_t[i0] == seg_t[i1 - 1]) {
                    float ca = 0.f, cb = 0.f, ca2 = 0.f, cb2 = 0.f;
                    #pragma unroll
                    for (int i2 = 0; i2 < 16; i2 += 2) {
                        int i = i0 + i2;
                        unsigned v0 = Ab32[(i + 0) * 128 + (((p >> 2) ^ ((i + 0) & 7)) << 2) + (p & 3)];
                        unsigned v1 = Ab32[(i + 1) * 128 + (((p >> 2) ^ ((i + 1) & 7)) << 2) + (p & 3)];
                        float a0 = alpha_s[i + 0], a1 = alpha_s[i + 1];
                        ca  += __uint_as_float(v0 << 16) * a0;
                        cb  += __uint_as_float(v0 & 0xffff0000u) * a0;
                        ca2 += __uint_as_float(v1 << 16) * a1;
                        cb2 += __uint_as_float(v1 & 0xffff0000u) * a1;
                    }
                    rb_p = (long)seg_t[i0] * D + 2 * p;
                    ca_p = ca + ca2; cb_p = cb + cb2;
                } else {
                    float ca = 0.f, cb = 0.f;
                    int curseg = seg_t[i0];
                    for (int i = i0; i < i1; ++i) {
                        int sgi = seg_t[i];
                        if (sgi != curseg) {
                            long rb = (long)curseg * D + 2 * p;
                            atomicAdd(&rst[rb], ca); atomicAdd(&rst[rb + 1], cb);
                            ca = cb = 0.f; curseg = sgi;
                        }
                        unsigned v = Ab32[i * 128 + (((p >> 2) ^ (i & 7)) << 2) + (p & 3)];
                        float al = alpha_s[i];
                        ca += __uint_as_float(v << 16) * al;
                        cb += __uint_as_float(v & 0xffff0000u) * al;
                    }
                    rb_p = (long)curseg * D + 2 * p;
                    ca_p = ca; cb_p = cb;
                }
            }
        }
        asm volatile("" ::: "memory");

        // s5: the ONE structural wait — retires dma(t+1) (streamed a full
        //     iteration), last iter's atomics, and STAGE(t+1)'s seg/cnt dma4.
        if (more1) {
            asm volatile("s_waitcnt vmcnt(0)" ::: "memory");
            CONVERT((tt + 1) & 1);
        }

        // s6: fvr(t+1) — seg_s[(t+1)&3] retired by the vmcnt(0) above
        if (more1) {
            const int* sn = seg_s[(tt + 1) & 3];
            #pragma unroll
            for (int nt = 0; nt < 4; ++nt) {
                int sg = sn[nt * 16 + rl];
                const float* fb = featv + (long)sg * D + 32 * w + h * 4;
                fvr[0][nt] = *(const f32x4*)(fb);
                fvr[1][nt] = *(const f32x4*)(fb + 16);
            }
            asm volatile("" ::: "memory");
        }

        // s7: deferred atomics (never manually waited until next iter's s5,
        //     by which time they are a full iteration old)
        if (rb_p >= 0) {
            atomicAdd(&rst[rb_p], ca_p);
            atomicAdd(&rst[rb_p + 1], cb_p);
        }
        asm volatile("" ::: "memory");

        // s8: issue DMA for tile t+2 (streams across all of iter t+1)
        if (more2) {
            STAGE(tt + 2);
            asm volatile("" ::: "memory");
        }

        // s9: close iteration (convert writes visible to all waves)
        BAR_LGKM;                                                       // b3
    }
#undef STAGE
#undef CONVERT
}

extern "C" void kernel_launch(void* const* d_in, const int* in_sizes, int n_in,
                              void* d_out, int out_size, void* d_ws, size_t ws_size,
                              hipStream_t stream) {
    const float* feat = (const float*)d_in[0];
    const float* cnt  = (const float*)d_in[1];
    const int*   segp = (const int*)d_in[2];
    const int*   last = (const int*)d_in[3];
    const float* Wu   = (const float*)d_in[4];
    const float* Wv   = (const float*)d_in[5];
    const float* bv   = (const float*)d_in[6];
    const float* we   = (const float*)d_in[7];
    float* rst = (float*)d_out;

    const int N    = in_sizes[1];
    const int Bseg = in_sizes[3];

    unsigned short* Wub   = (unsigned short*)d_ws;
    float*          featv = (float*)((char*)d_ws + (size_t)D * D * sizeof(unsigned short));

    const int zero_blocks = (out_size + 1023) / 1024;
    k_prep<<<384 + zero_blocks, 256, 0, stream>>>(feat, last, Wv, bv, Wu, Wub, featv, rst, Bseg, out_size);
    k_main<<<GRID_MAIN, 512, 0, stream>>>(feat, cnt, segp, Wub, featv, we, rst, N);
}

// Round 16
// 189.908 us; speedup vs baseline: 2.9686x; 1.0028x over previous
//
#include <hip/hip_runtime.h>
#include <hip/hip_bf16.h>

typedef __attribute__((ext_vector_type(8))) short short8;
typedef __attribute__((ext_vector_type(4))) float f32x4;

#define D 256
#define MT 64
#define NW 8
#define GRID_MAIN 256
#define GV 16

#define BAR_LGKM asm volatile("s_waitcnt lgkmcnt(0)\ns_barrier" ::: "memory")

__device__ __forceinline__ unsigned pack2(float a, float b) {
    __hip_bfloat162 hh = __float22bfloat162_rn(make_float2(a, b));
    return *(unsigned*)&hh;
}
__device__ __forceinline__ float fast_sigmoid(float x) {
    return __builtin_amdgcn_rcpf(1.f + __expf(-x));
}
__device__ __forceinline__ void dma16(const void* g, void* lds) {
    __builtin_amdgcn_global_load_lds((const __attribute__((address_space(1))) unsigned int*)g,
                                     (__attribute__((address_space(3))) unsigned int*)lds, 16, 0, 0);
}
__device__ __forceinline__ void dma4(const void* g, void* lds) {
    __builtin_amdgcn_global_load_lds((const __attribute__((address_space(1))) unsigned int*)g,
                                     (__attribute__((address_space(3))) unsigned int*)lds, 4, 0, 0);
}

// K0: fused prep. blocks [0,128): feat_v ; [128,384): W_u->bf16 ; [384,...): zero rst
__global__ __launch_bounds__(256) void k_prep(
    const float* __restrict__ feat, const int* __restrict__ last_nodes,
    const float* __restrict__ Wv, const float* __restrict__ bv,
    const float* __restrict__ Wu, unsigned short* __restrict__ Wub,
    float* __restrict__ featv, float* __restrict__ rst, int Bseg, int nOut) {
    const int b = blockIdx.x;
    const int t = threadIdx.x;
    if (b < 128) {
        __shared__ float fln[GV][D];
        const int b0 = b * GV;
        for (int g = 0; g < GV; ++g) {
            int bb = b0 + g;
            int ln = (bb < Bseg) ? last_nodes[bb] : 0;
            fln[g][t] = feat[(long)ln * D + t];
        }
        __syncthreads();
        float acc[GV];
        float bvj = bv[t];
        #pragma unroll
        for (int g = 0; g < GV; ++g) acc[g] = bvj;
        const float* wr = Wv + (long)t * D;
        for (int k = 0; k < D; k += 4) {
            float4 w4 = *(const float4*)(wr + k);
            #pragma unroll
            for (int g = 0; g < GV; ++g) {
                acc[g] += w4.x * fln[g][k]     + w4.y * fln[g][k + 1]
                        + w4.z * fln[g][k + 2] + w4.w * fln[g][k + 3];
            }
        }
        for (int g = 0; g < GV; ++g)
            if (b0 + g < Bseg) featv[(long)(b0 + g) * D + t] = acc[g];
    } else if (b < 384) {
        int i = (b - 128) * 256 + t;
        if (i < D * D) Wub[i] = (unsigned short)(pack2(Wu[i], 0.f) & 0xffffu);
    } else {
        int base = (b - 384) * 1024 + t;
        #pragma unroll
        for (int it = 0; it < 4; ++it) {
            int i = base + it * 256;
            if (i < nOut) rst[i] = 0.f;
        }
    }
}

// K2: persistent fused kernel (round-10 skeleton, wait-minimized).
//   DMA(t+1) streams fp32 feat -> linear stage across a FULL iteration;
//   convert (post-P4) builds the bf16 XOR-swizzled tile for iter t+1.
//   Manual waits: ONLY the pre-convert vmcnt(0) (retires one-iteration-old
//   DMA/atomics). Register-destined loads rely on compiler counted waits.
//   Iter tail order: convert -> fvr(t+1) -> deferred atomics -> STAGE(t+2).
__global__ __launch_bounds__(512, 2) void k_main(
    const float* __restrict__ feat, const float* __restrict__ cnt,
    const int* __restrict__ seg, const unsigned short* __restrict__ Wub,
    const float* __restrict__ featv, const float* __restrict__ we,
    float* __restrict__ rst, int N) {

    __shared__ float stageF[MT][D];              // 64 KB, linear DMA dest
    __shared__ unsigned short Abuf[2][MT][D];    // 64 KB, swizzled bf16
    __shared__ int   seg_s[4][MT];               // 4 slots: overwrite-race-free
    __shared__ float cnt_s[4][MT];
    __shared__ float e_s[NW][MT];
    __shared__ float alpha_s[MT];

    const int t  = threadIdx.x;
    const int w  = t >> 6;
    const int l  = t & 63;
    const int rl = l & 15;
    const int h  = l >> 4;

    const int T   = (N + MT - 1) / MT;
    const int nb  = gridDim.x;
    const int per = T / nb, rem = T % nb;
    const int bid = blockIdx.x;
    const int c0  = bid * per + (bid < rem ? bid : rem);
    const int c1  = c0 + per + (bid < rem ? 1 : 0);
    if (c0 >= c1) return;

#define STAGE(ti)                                                             \
    {                                                                         \
        const long nb0 = (long)(ti) * MT;                                     \
        long nsx = nb0 + l; if (nsx > (long)N - 1) nsx = (long)N - 1;         \
        dma4(seg + nsx, &seg_s[(ti) & 3][0]);                                 \
        dma4(cnt + nsx, &cnt_s[(ti) & 3][0]);                                 \
        asm volatile("" ::: "memory");                                        \
        _Pragma("unroll")                                                     \
        for (int i = 0; i < 8; ++i) {                                         \
            int r = w + 8 * i;                                                \
            long nn = nb0 + r; if (nn > (long)N - 1) nn = (long)N - 1;        \
            dma16(feat + nn * D + 4 * l, &stageF[r][0]);                      \
        }                                                                     \
    }

#define CONVERT(buf)                                                          \
    {                                                                         \
        _Pragma("unroll")                                                     \
        for (int i = 0; i < 8; ++i) {                                         \
            int r = w + 8 * i;                                                \
            f32x4 fv = *(const f32x4*)&stageF[r][4 * l];                      \
            *(uint2*)&Abuf[buf][r][(((l >> 1) ^ (r & 7)) << 3) + ((l & 1) << 2)] = \
                make_uint2(pack2(fv[0], fv[1]), pack2(fv[2], fv[3]));         \
        }                                                                     \
    }

    // W_u rows [32w, 32w+32) resident in registers (64 VGPR)
    short8 a_reg[2][8];
    {
        const unsigned short* ab = Wub + (long)(32 * w + rl) * D + h * 8;
        #pragma unroll
        for (int mt = 0; mt < 2; ++mt)
            #pragma unroll
            for (int s = 0; s < 8; ++s)
                a_reg[mt][s] = *(const short8*)(ab + (long)mt * 16 * D + s * 32);
    }
    f32x4 wev[2];
    wev[0] = *(const f32x4*)(we + 32 * w + h * 4);
    wev[1] = *(const f32x4*)(we + 32 * w + 16 + h * 4);

    // ---- prologue ----
    f32x4 fvr[2][4];
    STAGE(c0);
    asm volatile("s_waitcnt vmcnt(0)" ::: "memory");
    CONVERT(c0 & 1);
    {
        #pragma unroll
        for (int nt = 0; nt < 4; ++nt) {
            int sg = seg_s[c0 & 3][nt * 16 + rl];
            const float* fb = featv + (long)sg * D + 32 * w + h * 4;
            fvr[0][nt] = *(const f32x4*)(fb);
            fvr[1][nt] = *(const f32x4*)(fb + 16);
        }
    }
    asm volatile("" ::: "memory");
    if (c0 + 1 < c1) STAGE(c0 + 1);
    BAR_LGKM;

    for (int tt = c0; tt < c1; ++tt) {
        const long n0 = (long)tt * MT;
        const bool more1 = (tt + 1 < c1);
        const bool more2 = (tt + 2 < c1);
        const int  cur   = tt & 1;
        const int* seg_t = seg_s[tt & 3];

        // s1: MFMA u[j][node]; A from regs, B from bf16 swizzled LDS.
        //     No manual vmem wait: Abuf[cur] was converted + barriered.
        f32x4 acc[2][4];
        #pragma unroll
        for (int mt = 0; mt < 2; ++mt)
            #pragma unroll
            for (int nt = 0; nt < 4; ++nt) acc[mt][nt] = (f32x4)0.f;

        const unsigned short* Ab = &Abuf[cur][0][0];
        #pragma unroll
        for (int s = 0; s < 8; ++s) {
            short8 bfr[4];
            #pragma unroll
            for (int nt = 0; nt < 4; ++nt) {
                int R  = nt * 16 + rl;
                int gr = (s * 4 + h) ^ (rl & 7);
                bfr[nt] = *(const short8*)(Ab + R * D + gr * 8);
            }
            #pragma unroll
            for (int mt = 0; mt < 2; ++mt)
                #pragma unroll
                for (int nt = 0; nt < 4; ++nt)
                    acc[mt][nt] = __builtin_amdgcn_mfma_f32_16x16x32_bf16(a_reg[mt][s], bfr[nt], acc[mt][nt], 0, 0, 0);
        }

        // s2: epilogue; lane's j = 32w + 16mt + 4h + r, node = 16nt + rl
        //     (compiler inserts the counted wait for fvr's loads here)
        float ep[4] = {0.f, 0.f, 0.f, 0.f};
        #pragma unroll
        for (int mt = 0; mt < 2; ++mt)
            #pragma unroll
            for (int nt = 0; nt < 4; ++nt)
                #pragma unroll
                for (int r = 0; r < 4; ++r)
                    ep[nt] += wev[mt][r] * fast_sigmoid(acc[mt][nt][r] + fvr[mt][nt][r]);
        #pragma unroll
        for (int nt = 0; nt < 4; ++nt) {
            ep[nt] += __shfl_xor(ep[nt], 16);
            ep[nt] += __shfl_xor(ep[nt], 32);
        }
        if (h == 0) {
            #pragma unroll
            for (int nt = 0; nt < 4; ++nt) e_s[w][nt * 16 + rl] = ep[nt];
        }
        BAR_LGKM;                                                       // b1

        // s3: alpha (cnt_s[tt&3] retired by the pre-convert vmcnt(0) last iter)
        if (t < MT) {
            float e = 0.f;
            #pragma unroll
            for (int q = 0; q < NW; ++q) e += e_s[q][t];
            alpha_s[t] = (n0 + t < N) ? e * cnt_s[tt & 3][t] : 0.f;
        }
        BAR_LGKM;                                                       // b2

        // s4: P4 segment-sum from bf16 tile; final atomic pair deferred
        long rb_p = -1; float ca_p = 0.f, cb_p = 0.f;
        {
            const int p   = t & 127;
            const int gq  = t >> 7;
            const int i0  = gq * 16;
            const int nv  = (int)(((long)N - n0 < MT) ? ((long)N - n0) : MT);
            const int i1  = (i0 + 16 < nv) ? (i0 + 16) : nv;
            const unsigned* Ab32 = (const unsigned*)Ab;
            if (i0 < i1) {
                if ((i1 - i0) == 16 && seg_t[i0] == seg_t[i1 - 1]) {
                    float ca = 0.f, cb = 0.f, ca2 = 0.f, cb2 = 0.f;
                    #pragma unroll
                    for (int i2 = 0; i2 < 16; i2 += 2) {
                        int i = i0 + i2;
                        unsigned v0 = Ab32[(i + 0) * 128 + (((p >> 2) ^ ((i + 0) & 7)) << 2) + (p & 3)];
                        unsigned v1 = Ab32[(i + 1) * 128 + (((p >> 2) ^ ((i + 1) & 7)) << 2) + (p & 3)];
                        float a0 = alpha_s[i + 0], a1 = alpha_s[i + 1];
                        ca  += __uint_as_float(v0 << 16) * a0;
                        cb  += __uint_as_float(v0 & 0xffff0000u) * a0;
                        ca2 += __uint_as_float(v1 << 16) * a1;
                        cb2 += __uint_as_float(v1 & 0xffff0000u) * a1;
                    }
                    rb_p = (long)seg_t[i0] * D + 2 * p;
                    ca_p = ca + ca2; cb_p = cb + cb2;
                } else {
                    float ca = 0.f, cb = 0.f;
                    int curseg = seg_t[i0];
                    for (int i = i0; i < i1; ++i) {
                        int sgi = seg_t[i];
                        if (sgi != curseg) {
                            long rb = (long)curseg * D + 2 * p;
                            atomicAdd(&rst[rb], ca); atomicAdd(&rst[rb + 1], cb);
                            ca = cb = 0.f; curseg = sgi;
                        }
                        unsigned v = Ab32[i * 128 + (((p >> 2) ^ (i & 7)) << 2) + (p & 3)];
                        float al = alpha_s[i];
                        ca += __uint_as_float(v << 16) * al;
                        cb += __uint_as_float(v & 0xffff0000u) * al;
                    }
                    rb_p = (long)curseg * D + 2 * p;
                    ca_p = ca; cb_p = cb;
                }
            }
        }
        asm volatile("" ::: "memory");

        // s5: the ONE structural wait — retires dma(t+1) (streamed a full
        //     iteration), last iter's atomics, and STAGE(t+1)'s seg/cnt dma4.
        if (more1) {
            asm volatile("s_waitcnt vmcnt(0)" ::: "memory");
            CONVERT((tt + 1) & 1);
        }

        // s6: fvr(t+1) — seg_s[(t+1)&3] retired by the vmcnt(0) above
        if (more1) {
            const int* sn = seg_s[(tt + 1) & 3];
            #pragma unroll
            for (int nt = 0; nt < 4; ++nt) {
                int sg = sn[nt * 16 + rl];
                const float* fb = featv + (long)sg * D + 32 * w + h * 4;
                fvr[0][nt] = *(const f32x4*)(fb);
                fvr[1][nt] = *(const f32x4*)(fb + 16);
            }
            asm volatile("" ::: "memory");
        }

        // s7: deferred atomics (never manually waited until next iter's s5,
        //     by which time they are a full iteration old)
        if (rb_p >= 0) {
            atomicAdd(&rst[rb_p], ca_p);
            atomicAdd(&rst[rb_p + 1], cb_p);
        }
        asm volatile("" ::: "memory");

        // s8: issue DMA for tile t+2 (streams across all of iter t+1)
        if (more2) {
            STAGE(tt + 2);
            asm volatile("" ::: "memory");
        }

        // s9: close iteration (convert writes visible to all waves)
        BAR_LGKM;                                                       // b3
    }
#undef STAGE
#undef CONVERT
}

extern "C" void kernel_launch(void* const* d_in, const int* in_sizes, int n_in,
                              void* d_out, int out_size, void* d_ws, size_t ws_size,
                              hipStream_t stream) {
    const float* feat = (const float*)d_in[0];
    const float* cnt  = (const float*)d_in[1];
    const int*   segp = (const int*)d_in[2];
    const int*   last = (const int*)d_in[3];
    const float* Wu   = (const float*)d_in[4];
    const float* Wv   = (const float*)d_in[5];
    const float* bv   = (const float*)d_in[6];
    const float* we   = (const float*)d_in[7];
    float* rst = (float*)d_out;

    const int N    = in_sizes[1];
    const int Bseg = in_sizes[3];

    unsigned short* Wub   = (unsigned short*)d_ws;
    float*          featv = (float*)((char*)d_ws + (size_t)D * D * sizeof(unsigned short));

    const int zero_blocks = (out_size + 1023) / 1024;
    k_prep<<<384 + zero_blocks, 256, 0, stream>>>(feat, last, Wv, bv, Wu, Wub, featv, rst, Bseg, out_size);
    k_main<<<GRID_MAIN, 512, 0, stream>>>(feat, cnt, segp, Wub, featv, we, rst, N);
}

// Round 17
// 178.694 us; speedup vs baseline: 3.1549x; 1.0628x over previous
//
#include <hip/hip_runtime.h>
#include <hip/hip_bf16.h>

typedef __attribute__((ext_vector_type(8))) short short8;
typedef __attribute__((ext_vector_type(4))) float f32x4;

#define D 256
#define MT 64
#define NW 8
#define GRID_MAIN 256
#define GV 8

#define BAR_LGKM asm volatile("s_waitcnt lgkmcnt(0)\ns_barrier" ::: "memory")

__device__ __forceinline__ unsigned pack2(float a, float b) {
    __hip_bfloat162 hh = __float22bfloat162_rn(make_float2(a, b));
    return *(unsigned*)&hh;
}
__device__ __forceinline__ float fast_sigmoid(float x) {
    return __builtin_amdgcn_rcpf(1.f + __expf(-x));
}
__device__ __forceinline__ void dma16(const void* g, void* lds) {
    __builtin_amdgcn_global_load_lds((const __attribute__((address_space(1))) unsigned int*)g,
                                     (__attribute__((address_space(3))) unsigned int*)lds, 16, 0, 0);
}
__device__ __forceinline__ void dma4(const void* g, void* lds) {
    __builtin_amdgcn_global_load_lds((const __attribute__((address_space(1))) unsigned int*)g,
                                     (__attribute__((address_space(3))) unsigned int*)lds, 4, 0, 0);
}

// P4: weighted segment-sum of one (already-consumed) tile from the bf16
// XOR-swizzled LDS image. thread p<128 owns dims {2p,2p+1}; gq rows [16gq,+16).
// Final atomic pair is returned (deferred); interior boundaries flushed inline.
__device__ __forceinline__ void p4_run(
    const unsigned* __restrict__ Ab32, const float* __restrict__ al_s,
    const int* __restrict__ seg_t, long n0, int N, int t,
    float* __restrict__ rst, long& rb_p, float& ca_p, float& cb_p) {
    const int p   = t & 127;
    const int gq  = t >> 7;
    const int i0  = gq * 16;
    const int nv  = (int)(((long)N - n0 < MT) ? ((long)N - n0) : MT);
    const int i1  = (i0 + 16 < nv) ? (i0 + 16) : nv;
    rb_p = -1; ca_p = 0.f; cb_p = 0.f;
    if (i0 >= i1) return;
    if ((i1 - i0) == 16 && seg_t[i0] == seg_t[i1 - 1]) {
        float ca = 0.f, cb = 0.f, ca2 = 0.f, cb2 = 0.f;
        #pragma unroll
        for (int i2 = 0; i2 < 16; i2 += 2) {
            int i = i0 + i2;
            unsigned v0 = Ab32[(i + 0) * 128 + (((p >> 2) ^ ((i + 0) & 7)) << 2) + (p & 3)];
            unsigned v1 = Ab32[(i + 1) * 128 + (((p >> 2) ^ ((i + 1) & 7)) << 2) + (p & 3)];
            float a0 = al_s[i + 0], a1 = al_s[i + 1];
            ca  += __uint_as_float(v0 << 16) * a0;
            cb  += __uint_as_float(v0 & 0xffff0000u) * a0;
            ca2 += __uint_as_float(v1 << 16) * a1;
            cb2 += __uint_as_float(v1 & 0xffff0000u) * a1;
        }
        rb_p = (long)seg_t[i0] * D + 2 * p;
        ca_p = ca + ca2; cb_p = cb + cb2;
    } else {
        float ca = 0.f, cb = 0.f;
        int curseg = seg_t[i0];
        for (int i = i0; i < i1; ++i) {
            int sgi = seg_t[i];
            if (sgi != curseg) {
                long rb = (long)curseg * D + 2 * p;
                atomicAdd(&rst[rb], ca); atomicAdd(&rst[rb + 1], cb);
                ca = cb = 0.f; curseg = sgi;
            }
            unsigned v = Ab32[i * 128 + (((p >> 2) ^ (i & 7)) << 2) + (p & 3)];
            float al = al_s[i];
            ca += __uint_as_float(v << 16) * al;
            cb += __uint_as_float(v & 0xffff0000u) * al;
        }
        rb_p = (long)curseg * D + 2 * p;
        ca_p = ca; cb_p = cb;
    }
}

// K0: fused prep. blocks [0,256): feat_v (GV=8 -> full-GPU parallelism);
//     [256,512): W_u->bf16 ; [512,...): zero rst
__global__ __launch_bounds__(256) void k_prep(
    const float* __restrict__ feat, const int* __restrict__ last_nodes,
    const float* __restrict__ Wv, const float* __restrict__ bv,
    const float* __restrict__ Wu, unsigned short* __restrict__ Wub,
    float* __restrict__ featv, float* __restrict__ rst, int Bseg, int nOut) {
    const int b = blockIdx.x;
    const int t = threadIdx.x;
    if (b < 256) {
        __shared__ float fln[GV][D];
        const int b0 = b * GV;
        for (int g = 0; g < GV; ++g) {
            int bb = b0 + g;
            int ln = (bb < Bseg) ? last_nodes[bb] : 0;
            fln[g][t] = feat[(long)ln * D + t];
        }
        __syncthreads();
        float acc[GV];
        float bvj = bv[t];
        #pragma unroll
        for (int g = 0; g < GV; ++g) acc[g] = bvj;
        const float* wr = Wv + (long)t * D;
        for (int k = 0; k < D; k += 4) {
            float4 w4 = *(const float4*)(wr + k);
            #pragma unroll
            for (int g = 0; g < GV; ++g) {
                acc[g] += w4.x * fln[g][k]     + w4.y * fln[g][k + 1]
                        + w4.z * fln[g][k + 2] + w4.w * fln[g][k + 3];
            }
        }
        for (int g = 0; g < GV; ++g)
            if (b0 + g < Bseg) featv[(long)(b0 + g) * D + t] = acc[g];
    } else if (b < 512) {
        int i = (b - 256) * 256 + t;
        if (i < D * D) Wub[i] = (unsigned short)(pack2(Wu[i], 0.f) & 0xffffu);
    } else {
        int base = (b - 512) * 1024 + t;
        #pragma unroll
        for (int it = 0; it < 4; ++it) {
            int i = base + it * 256;
            if (i < nOut) rst[i] = 0.f;
        }
    }
}

// K2: persistent fused kernel — round-16 skeleton with P4 pipelined one tile
// back (2 barriers/iter):
//   MFMA(t) | epilogue(t) | P4(t-1) | b1 | alpha(t) | vmcnt(0) | convert(t+1)
//   | fvr(t+1) | atomics(t-1) | STAGE(t+2) | b2
// Buffer fencing: P4(t-1) reads Abuf[(t-1)&1], which convert(t+1) rewrites
// post-b1 (same parity). alpha_s is 2-deep ping-pong. seg slots rotate mod 4.
__global__ __launch_bounds__(512, 2) void k_main(
    const float* __restrict__ feat, const float* __restrict__ cnt,
    const int* __restrict__ seg, const unsigned short* __restrict__ Wub,
    const float* __restrict__ featv, const float* __restrict__ we,
    float* __restrict__ rst, int N) {

    __shared__ float stageF[MT][D];              // 64 KB, linear DMA dest
    __shared__ unsigned short Abuf[2][MT][D];    // 64 KB, swizzled bf16
    __shared__ int   seg_s[4][MT];
    __shared__ float cnt_s[4][MT];
    __shared__ float e_s[NW][MT];
    __shared__ float alpha_s[2][MT];             // ping-pong (P4 lags one tile)

    const int t  = threadIdx.x;
    const int w  = t >> 6;
    const int l  = t & 63;
    const int rl = l & 15;
    const int h  = l >> 4;

    const int T   = (N + MT - 1) / MT;
    const int nb  = gridDim.x;
    const int per = T / nb, rem = T % nb;
    const int bid = blockIdx.x;
    const int c0  = bid * per + (bid < rem ? bid : rem);
    const int c1  = c0 + per + (bid < rem ? 1 : 0);
    if (c0 >= c1) return;

#define STAGE(ti)                                                             \
    {                                                                         \
        const long nb0 = (long)(ti) * MT;                                     \
        long nsx = nb0 + l; if (nsx > (long)N - 1) nsx = (long)N - 1;         \
        dma4(seg + nsx, &seg_s[(ti) & 3][0]);                                 \
        dma4(cnt + nsx, &cnt_s[(ti) & 3][0]);                                 \
        asm volatile("" ::: "memory");                                        \
        _Pragma("unroll")                                                     \
        for (int i = 0; i < 8; ++i) {                                         \
            int r = w + 8 * i;                                                \
            long nn = nb0 + r; if (nn > (long)N - 1) nn = (long)N - 1;        \
            dma16(feat + nn * D + 4 * l, &stageF[r][0]);                      \
        }                                                                     \
    }

#define CONVERT(buf)                                                          \
    {                                                                         \
        _Pragma("unroll")                                                     \
        for (int i = 0; i < 8; ++i) {                                         \
            int r = w + 8 * i;                                                \
            f32x4 fv = *(const f32x4*)&stageF[r][4 * l];                      \
            *(uint2*)&Abuf[buf][r][(((l >> 1) ^ (r & 7)) << 3) + ((l & 1) << 2)] = \
                make_uint2(pack2(fv[0], fv[1]), pack2(fv[2], fv[3]));         \
        }                                                                     \
    }

    // W_u rows [32w, 32w+32) resident in registers (64 VGPR)
    short8 a_reg[2][8];
    {
        const unsigned short* ab = Wub + (long)(32 * w + rl) * D + h * 8;
        #pragma unroll
        for (int mt = 0; mt < 2; ++mt)
            #pragma unroll
            for (int s = 0; s < 8; ++s)
                a_reg[mt][s] = *(const short8*)(ab + (long)mt * 16 * D + s * 32);
    }
    f32x4 wev[2];
    wev[0] = *(const f32x4*)(we + 32 * w + h * 4);
    wev[1] = *(const f32x4*)(we + 32 * w + 16 + h * 4);

    // ---- prologue ----
    f32x4 fvr[2][4];
    STAGE(c0);
    asm volatile("s_waitcnt vmcnt(0)" ::: "memory");
    CONVERT(c0 & 1);
    {
        #pragma unroll
        for (int nt = 0; nt < 4; ++nt) {
            int sg = seg_s[c0 & 3][nt * 16 + rl];
            const float* fb = featv + (long)sg * D + 32 * w + h * 4;
            fvr[0][nt] = *(const f32x4*)(fb);
            fvr[1][nt] = *(const f32x4*)(fb + 16);
        }
    }
    asm volatile("" ::: "memory");
    if (c0 + 1 < c1) STAGE(c0 + 1);
    BAR_LGKM;

    for (int tt = c0; tt < c1; ++tt) {
        const long n0 = (long)tt * MT;
        const bool more1 = (tt + 1 < c1);
        const bool more2 = (tt + 2 < c1);
        const int  cur   = tt & 1;

        // s1: MFMA u[j][node]; A from regs, B from bf16 swizzled LDS
        f32x4 acc[2][4];
        #pragma unroll
        for (int mt = 0; mt < 2; ++mt)
            #pragma unroll
            for (int nt = 0; nt < 4; ++nt) acc[mt][nt] = (f32x4)0.f;

        const unsigned short* Ab = &Abuf[cur][0][0];
        #pragma unroll
        for (int s = 0; s < 8; ++s) {
            short8 bfr[4];
            #pragma unroll
            for (int nt = 0; nt < 4; ++nt) {
                int R  = nt * 16 + rl;
                int gr = (s * 4 + h) ^ (rl & 7);
                bfr[nt] = *(const short8*)(Ab + R * D + gr * 8);
            }
            #pragma unroll
            for (int mt = 0; mt < 2; ++mt)
                #pragma unroll
                for (int nt = 0; nt < 4; ++nt)
                    acc[mt][nt] = __builtin_amdgcn_mfma_f32_16x16x32_bf16(a_reg[mt][s], bfr[nt], acc[mt][nt], 0, 0, 0);
        }

        // s2: epilogue(t); lane's j = 32w + 16mt + 4h + r, node = 16nt + rl
        float ep[4] = {0.f, 0.f, 0.f, 0.f};
        #pragma unroll
        for (int mt = 0; mt < 2; ++mt)
            #pragma unroll
            for (int nt = 0; nt < 4; ++nt)
                #pragma unroll
                for (int r = 0; r < 4; ++r)
                    ep[nt] += wev[mt][r] * fast_sigmoid(acc[mt][nt][r] + fvr[mt][nt][r]);
        #pragma unroll
        for (int nt = 0; nt < 4; ++nt) {
            ep[nt] += __shfl_xor(ep[nt], 16);
            ep[nt] += __shfl_xor(ep[nt], 32);
        }
        if (h == 0) {
            #pragma unroll
            for (int nt = 0; nt < 4; ++nt) e_s[w][nt * 16 + rl] = ep[nt];
        }

        // s3: P4(t-1) — same barrier interval as MFMA/epilogue (acc/fvr dead).
        //     Reads Abuf[(t-1)&1] + alpha_s[(t-1)&1]; convert(t+1) rewrites
        //     that Abuf parity only after b1.
        long rb_p = -1; float ca_p = 0.f, cb_p = 0.f;
        if (tt > c0) {
            p4_run((const unsigned*)&Abuf[(tt - 1) & 1][0][0],
                   alpha_s[(tt - 1) & 1], seg_s[(tt - 1) & 3],
                   (long)(tt - 1) * MT, N, t, rst, rb_p, ca_p, cb_p);
        }
        BAR_LGKM;                                                       // b1

        // s4: alpha(t) -> alpha_s[t&1]
        if (t < MT) {
            float e = 0.f;
            #pragma unroll
            for (int q = 0; q < NW; ++q) e += e_s[q][t];
            alpha_s[cur][t] = (n0 + t < N) ? e * cnt_s[tt & 3][t] : 0.f;
        }

        // s5: the ONE structural wait — retires STAGE(t+1)'s DMA (streamed a
        //     full iteration) and atomics(t-2). Nothing fresh.
        if (more1) {
            asm volatile("s_waitcnt vmcnt(0)" ::: "memory");
            CONVERT((tt + 1) & 1);
        }

        // s6: fvr(t+1) — seg_s[(t+1)&3] retired by the vmcnt(0) above
        if (more1) {
            const int* sn = seg_s[(tt + 1) & 3];
            #pragma unroll
            for (int nt = 0; nt < 4; ++nt) {
                int sg = sn[nt * 16 + rl];
                const float* fb = featv + (long)sg * D + 32 * w + h * 4;
                fvr[0][nt] = *(const f32x4*)(fb);
                fvr[1][nt] = *(const f32x4*)(fb + 16);
            }
            asm volatile("" ::: "memory");
        }

        // s7: deferred atomics for tile t-1
        if (rb_p >= 0) {
            atomicAdd(&rst[rb_p], ca_p);
            atomicAdd(&rst[rb_p + 1], cb_p);
        }
        asm volatile("" ::: "memory");

        // s8: issue DMA for tile t+2 (streams across all of iter t+1)
        if (more2) {
            STAGE(tt + 2);
            asm volatile("" ::: "memory");
        }

        // s9: close iteration (alpha + convert visible to all waves)
        BAR_LGKM;                                                       // b2
    }

    // ---- tail: P4 + atomics for the final tile (c1-1) ----
    {
        const int lt = c1 - 1;
        long rb_p; float ca_p, cb_p;
        p4_run((const unsigned*)&Abuf[lt & 1][0][0],
               alpha_s[lt & 1], seg_s[lt & 3],
               (long)lt * MT, N, t, rst, rb_p, ca_p, cb_p);
        if (rb_p >= 0) {
            atomicAdd(&rst[rb_p], ca_p);
            atomicAdd(&rst[rb_p + 1], cb_p);
        }
    }
#undef STAGE
#undef CONVERT
}

extern "C" void kernel_launch(void* const* d_in, const int* in_sizes, int n_in,
                              void* d_out, int out_size, void* d_ws, size_t ws_size,
                              hipStream_t stream) {
    const float* feat = (const float*)d_in[0];
    const float* cnt  = (const float*)d_in[1];
    const int*   segp = (const int*)d_in[2];
    const int*   last = (const int*)d_in[3];
    const float* Wu   = (const float*)d_in[4];
    const float* Wv   = (const float*)d_in[5];
    const float* bv   = (const float*)d_in[6];
    const float* we   = (const float*)d_in[7];
    float* rst = (float*)d_out;

    const int N    = in_sizes[1];
    const int Bseg = in_sizes[3];

    unsigned short* Wub   = (unsigned short*)d_ws;
    float*          featv = (float*)((char*)d_ws + (size_t)D * D * sizeof(unsigned short));

    const int zero_blocks = (out_size + 1023) / 1024;
    k_prep<<<512 + zero_blocks, 256, 0, stream>>>(feat, last, Wv, bv, Wu, Wub, featv, rst, Bseg, out_size);
    k_main<<<GRID_MAIN, 512, 0, stream>>>(feat, cnt, segp, Wub, featv, we, rst, N);
}